// Round 7
// baseline (8159.618 us; speedup 1.0000x reference)
//
#include <hip/hip_runtime.h>
#include <cstddef>

#define B_  64
#define T_  256
#define I_  256
#define H_  1024
#define C_  1000
#define BH_ (B_ * H_)

typedef _Float16 f16;
typedef __attribute__((ext_vector_type(8))) _Float16 f16x8;
typedef __attribute__((ext_vector_type(4))) float f32x4;

__device__ __forceinline__ float sigmoid_(float v) { return 1.0f / (1.0f + __expf(-v)); }
__device__ __forceinline__ float tanh_(float v) {
  float e = __expf(-2.0f * fabsf(v));
  float t = (1.0f - e) / (1.0f + e);
  return copysignf(t, v);
}

// h store: agent-scope relaxed atomic store -> write-through dword (sc0 sc1).
// No dirty L2 lines; globally visible once vmcnt drains at __syncthreads.
__device__ __forceinline__ void storeH2(f16* p, float a, float b) {
  union { f16 h[2]; unsigned u; } pk;
  pk.h[0] = (f16)a; pk.h[1] = (f16)b;
  __hip_atomic_store((unsigned*)p, pk.u, __ATOMIC_RELAXED, __HIP_MEMORY_SCOPE_AGENT);
}

// h load: 4x4B agent-scope relaxed atomic loads (global_load_dword sc0 sc1 --
// bypass L1/L2, read the coherence point). This makes h reads fence-free
// correct with a 2-slot ring: no stale cached copy can ever be observed,
// because no cache is consulted. x16/weights keep normal cached loads and now
// PERSIST in L1/L2 across phases (no more per-phase invalidate).
__device__ __forceinline__ f16x8 loadH8(const f16* p) {
  const unsigned* q = (const unsigned*)p;
  union { unsigned u[4]; f16x8 v; } r;
  r.u[0] = __hip_atomic_load(q + 0, __ATOMIC_RELAXED, __HIP_MEMORY_SCOPE_AGENT);
  r.u[1] = __hip_atomic_load(q + 1, __ATOMIC_RELAXED, __HIP_MEMORY_SCOPE_AGENT);
  r.u[2] = __hip_atomic_load(q + 2, __ATOMIC_RELAXED, __HIP_MEMORY_SCOPE_AGENT);
  r.u[3] = __hip_atomic_load(q + 3, __ATOMIC_RELAXED, __HIP_MEMORY_SCOPE_AGENT);
  return r.v;
}

// Two-level barrier (R3 structure -- measured 3.5us/phase cheaper than flat),
// all RELAXED, and now with NO acquire fence: data coherence is carried by the
// cache-bypassing h loads, not by invalidation. Release ordering of h stores
// before the flag-add comes from __syncthreads' vmcnt(0) drain.
__device__ __forceinline__ void grid_barrier(unsigned* sync, int bid, int phase) {
  __syncthreads();
  if (threadIdx.x == 0) {
    unsigned* master = sync;
    unsigned* bucket = sync + 32 * (1 + (bid & 7));   // 128B-spaced lines
    __hip_atomic_fetch_add(bucket, 1u, __ATOMIC_RELAXED, __HIP_MEMORY_SCOPE_AGENT);
    if (bid < 8) {
      const unsigned bt = 32u * (unsigned)(phase + 1);
      int g = 0;
      while (__hip_atomic_load(bucket, __ATOMIC_RELAXED, __HIP_MEMORY_SCOPE_AGENT) < bt) {
        __builtin_amdgcn_s_sleep(1);
        if (++g > (1 << 16)) break;
      }
      __hip_atomic_fetch_add(master, 1u, __ATOMIC_RELAXED, __HIP_MEMORY_SCOPE_AGENT);
    }
    const unsigned mt = 8u * (unsigned)(phase + 1);
    int g2 = 0;
    while (__hip_atomic_load(master, __ATOMIC_RELAXED, __HIP_MEMORY_SCOPE_AGENT) < mt) {
      __builtin_amdgcn_s_sleep(1);
      if (++g2 > (1 << 16)) break;
    }
  }
  __syncthreads();
}

// One block = 512 threads = 8 waves = (K-split 4) x (N-split 2).
// Block tile: 32 batch rows x 64 gate-cols (4 gates x 16 units).
// Per-wave weights: (K/4) x 32 cols f16 = 128 VGPRs (L1) -> 2 waves/SIMD.
// CRITICAL: prologue loop must be FULLY unrolled so Wreg indexing is static
// (R2's `#pragma unroll 1` demoted Wreg to scratch -> 7 GB/launch re-fetch).
template<bool IS_L1>
__device__ __forceinline__ void role_main(
    const f16* __restrict__ x16,
    const float* __restrict__ Wx, const float* __restrict__ Wh,
    const float* __restrict__ bias,
    f16* __restrict__ h0buf, f16* __restrict__ h1buf,
    unsigned* sync, int bid,
    float* zbAll, float* cLDS, float* biasLDS)
{
  constexpr int KTOT = IS_L1 ? 64 : 40;   // k-tiles of 32 (L0: 8 x-tiles + 32 h-tiles)
  constexpr int NKT  = KTOT / 4;          // per-wave k-tiles (K-split over kq)
  constexpr int KX   = IS_L1 ? 1024 : 256;

  const int tid  = threadIdx.x;
  const int wv   = tid >> 6;          // 0..7
  const int nh   = wv >> 2;           // col-half (32 cols each)
  const int kq   = wv & 3;            // K quarter
  const int lane = tid & 63;
  const int c16  = lane & 15;
  const int quad = lane >> 4;
  const int rr7  = bid & 127;
  const int mgroup  = rr7 & 1;
  const int ubase   = (rr7 >> 1) * 16;
  const int rowbase = mgroup * 32;

  if (tid < 64) biasLDS[tid] = bias[(size_t)(tid >> 4) * H_ + ubase + (tid & 15)];
  cLDS[tid] = 0.0f;

  // ---- weight prologue: global fp32 -> per-wave LDS panel -> f16 B-frags in regs
  f16x8 Wreg[2][NKT];
  {
    f16* zpan = (f16*)zbAll + wv * 1024;   // private 2KB panel per wave
#pragma unroll
    for (int ii = 0; ii < NKT; ++ii) {
      const int kt = kq * NKT + ii;
#pragma unroll
      for (int rw = 0; rw < 16; ++rw) {
        const int krow  = rw * 2 + (lane >> 5);
        const int col32 = lane & 31;
        const int g = nh * 2 + (col32 >> 4);
        const int u = col32 & 15;
        const int k = kt * 32 + krow;
        float wval = (k < KX) ? Wx[((size_t)g * KX + k) * H_ + ubase + u]
                              : Wh[((size_t)g * H_ + (k - KX)) * H_ + ubase + u];
        zpan[krow * 32 + col32] = (f16)wval;
      }
#pragma unroll
      for (int nt = 0; nt < 2; ++nt) {
        f16x8 f;
#pragma unroll
        for (int j = 0; j < 8; ++j)
          f[j] = zpan[(quad * 8 + j) * 32 + nt * 16 + c16];  // B[n=lane&15][k=quad*8+j]
        Wreg[nt][ii] = f;
      }
    }
  }
  __syncthreads();

  const int ktbase = kq * NKT;
  const int row0 = rowbase + c16;

#pragma unroll 1
  for (int p = 0; p <= T_; ++p) {
    const bool active = IS_L1 ? (p >= 1) : (p < T_);
    if (active) {
      // 2-slot ring: h0[t] <-> slot (t+1)&1, h1[t] <-> slot (t+1)&1
      const int iA = p & 1;              // h0[p-1]
      const int iB = (p - 1) & 1;        // h1[p-2] (L1 only)
      const int iD = IS_L1 ? (p & 1) : ((p + 1) & 1);   // h1[p-1] / h0[p]
      const f16* __restrict__ hA = h0buf + (size_t)iA * BH_;
      const f16* __restrict__ hB = h1buf + (size_t)iB * BH_;
      f16* __restrict__ hdst = (IS_L1 ? h1buf : h0buf) + (size_t)iD * BH_;

      f16x8 Abuf[6][2];
      auto loadA = [&](int ii, int slot) {
        const int kt = ktbase + ii;
        const int k  = kt * 32 + quad * 8;
#pragma unroll
        for (int mt2 = 0; mt2 < 2; ++mt2) {
          const int row = row0 + mt2 * 16;
          if (!IS_L1 && k < 256) {          // x-part: immutable f16, CACHED
            Abuf[slot][mt2] = *(const f16x8*)(x16 + ((size_t)row * T_ + p) * I_ + k);
          } else if (IS_L1 && k >= 1024) {
            Abuf[slot][mt2] = loadH8(hB + (size_t)row * H_ + (k - 1024));
          } else {
            const int kk = IS_L1 ? k : (k - 256);
            Abuf[slot][mt2] = loadH8(hA + (size_t)row * H_ + kk);
          }
        }
      };

      f32x4 acc[2][2];
#pragma unroll
      for (int mt2 = 0; mt2 < 2; ++mt2)
#pragma unroll
        for (int nt = 0; nt < 2; ++nt)
          acc[mt2][nt] = (f32x4)0.0f;

      loadA(0, 0); loadA(1, 1); loadA(2, 2);
      loadA(3, 3); loadA(4, 4); loadA(5, 5);     // prefetch ring depth 6
#pragma unroll
      for (int i = 0; i < NKT; ++i) {
        const int sl = i % 6;
        const f16x8 a0 = Abuf[sl][0];
        const f16x8 a1 = Abuf[sl][1];
        if (i + 6 < NKT) loadA(i + 6, (i + 6) % 6);
        acc[0][0] = __builtin_amdgcn_mfma_f32_16x16x32_f16(a0, Wreg[0][i], acc[0][0], 0, 0, 0);
        acc[0][1] = __builtin_amdgcn_mfma_f32_16x16x32_f16(a0, Wreg[1][i], acc[0][1], 0, 0, 0);
        acc[1][0] = __builtin_amdgcn_mfma_f32_16x16x32_f16(a1, Wreg[0][i], acc[1][0], 0, 0, 0);
        acc[1][1] = __builtin_amdgcn_mfma_f32_16x16x32_f16(a1, Wreg[1][i], acc[1][1], 0, 0, 0);
      }

      // partial z -> LDS; region (nh*4 + kq) so stage-1 sums stride-1024 over kq
      float* zw = zbAll + (nh * 4 + kq) * 1024;
#pragma unroll
      for (int mt2 = 0; mt2 < 2; ++mt2)
#pragma unroll
        for (int nt = 0; nt < 2; ++nt)
#pragma unroll
          for (int e = 0; e < 4; ++e)
            zw[(mt2 * 2 + nt) * 256 + (quad * 4 + e) * 16 + c16] = acc[mt2][nt][e];

      __syncthreads();

      // stage 1: reduce 4 K-partials + bias, in place into kq=0 region
      {
        const int base = tid * 4;          // 512 thr x 4 = 2048 final z
        const int nh1  = base >> 10;
        const int off  = base & 1023;
        f32x4 s = (f32x4)0.0f;
#pragma unroll
        for (int q = 0; q < 4; ++q)
          s += *(const f32x4*)(zbAll + nh1 * 4096 + q * 1024 + off);
        const int nt1 = (off >> 8) & 1;
        const int c0  = off & 15;
        s += *(const f32x4*)(biasLDS + (nh1 * 2 + nt1) * 16 + c0);
        *(f32x4*)(zbAll + nh1 * 4096 + off) = s;
      }
      __syncthreads();

      // stage 2: fused gates; c stays in LDS; h published via write-through 4B stores
      {
        const int row = tid >> 4, u = tid & 15;
        const int mt2 = row >> 4, r16 = row & 15;
        const float z0 = zbAll[0 * 4096 + (mt2 * 2 + 0) * 256 + r16 * 16 + u];
        const float z1 = zbAll[0 * 4096 + (mt2 * 2 + 1) * 256 + r16 * 16 + u];
        const float z2 = zbAll[1 * 4096 + (mt2 * 2 + 0) * 256 + r16 * 16 + u];
        const float z3 = zbAll[1 * 4096 + (mt2 * 2 + 1) * 256 + r16 * 16 + u];
        const float cv = cLDS[tid];
        const float gt = tanh_(z0);
        const float iv = sigmoid_(z1);
        const float fv = sigmoid_(z2);
        const float ov = sigmoid_(z3);
        const float cn = gt * iv + cv * fv;
        cLDS[tid] = cn;
        const float hn = tanh_(cn) * ov;
        const float hn_hi = __shfl_down(hn, 1);
        if ((tid & 1) == 0)
          storeH2(hdst + (size_t)(rowbase + row) * H_ + ubase + u, hn, hn_hi);
      }
    } else {
      __syncthreads();   // keep barrier symmetry on inactive phases
    }
    grid_barrier(sync, bid, p);
  }
}

__global__ __launch_bounds__(512, 2)
void lstm_persistent(const f16* __restrict__ x16,
                     const float* __restrict__ W0x, const float* __restrict__ W0h, const float* __restrict__ b0,
                     const float* __restrict__ W1x, const float* __restrict__ W1h, const float* __restrict__ b1,
                     f16* h0buf, f16* h1buf, unsigned* sync)
{
  __shared__ float zbAll[8192];    // 32KB: prologue panels / wave partial z / final z
  __shared__ float cLDS[512];
  __shared__ float biasLDS[64];
  const int bid = blockIdx.x;
  if (bid >= 128)
    role_main<true >(x16, W1x, W1h, b1, h0buf, h1buf, sync, bid, zbAll, cLDS, biasLDS);
  else
    role_main<false>(x16, W0x, W0h, b0, h0buf, h1buf, sync, bid, zbAll, cLDS, biasLDS);
}

// x fp32 -> f16, once
__global__ void cvt_x(const float* __restrict__ xin, f16* __restrict__ xo)
{
  const int i = (blockIdx.x * 256 + threadIdx.x) * 8;
  const float4 a = *(const float4*)(xin + i);
  const float4 b = *(const float4*)(xin + i + 4);
  f16x8 v;
  v[0] = (f16)a.x; v[1] = (f16)a.y; v[2] = (f16)a.z; v[3] = (f16)a.w;
  v[4] = (f16)b.x; v[5] = (f16)b.y; v[6] = (f16)b.z; v[7] = (f16)b.w;
  *(f16x8*)(xo + i) = v;
}

// out[b][c] = h1_final[b][:] . Wo[:][c] + bo[c]   (fp32 vector math)
__global__ void out_gemm(const f16* __restrict__ h1,
                         const float* __restrict__ Wo, const float* __restrict__ bo,
                         float* __restrict__ out)
{
  __shared__ float ht[1024][8];
  const int tid = threadIdx.x;    // 128 threads
  const int b0r = blockIdx.y * 4;
  for (int i = tid; i < 4096; i += 128) {
    const int rr = i >> 10, k = i & 1023;
    ht[k][rr] = (float)h1[(size_t)(b0r + rr) * H_ + k];
  }
  __syncthreads();
  const int c = blockIdx.x * 125 + tid;
  if (tid < 125) {
    float a0 = 0.f, a1 = 0.f, a2 = 0.f, a3 = 0.f;
#pragma unroll 4
    for (int k = 0; k < 1024; ++k) {
      const float w = Wo[(size_t)k * C_ + c];
      a0 += ht[k][0] * w;
      a1 += ht[k][1] * w;
      a2 += ht[k][2] * w;
      a3 += ht[k][3] * w;
    }
    const float bb = bo[c];
    out[(size_t)(b0r + 0) * C_ + c] = a0 + bb;
    out[(size_t)(b0r + 1) * C_ + c] = a1 + bb;
    out[(size_t)(b0r + 2) * C_ + c] = a2 + bb;
    out[(size_t)(b0r + 3) * C_ + c] = a3 + bb;
  }
}

extern "C" void kernel_launch(void* const* d_in, const int* in_sizes, int n_in,
                              void* d_out, int out_size, void* d_ws, size_t ws_size,
                              hipStream_t stream)
{
  const float* x   = (const float*)d_in[0];
  const float* W0x = (const float*)d_in[1];
  const float* W0h = (const float*)d_in[2];
  const float* b0  = (const float*)d_in[3];
  const float* W1x = (const float*)d_in[4];
  const float* W1h = (const float*)d_in[5];
  const float* b1  = (const float*)d_in[6];
  const float* Wo  = (const float*)d_in[7];
  const float* bo  = (const float*)d_in[8];

  unsigned* sync = (unsigned*)d_ws;                        // barrier counters (4KB)
  f16* h0buf = (f16*)((char*)d_ws + 4096);                 // [2][64][1024] f16
  f16* h1buf = h0buf + 2 * BH_;                            // [2][64][1024] f16
  f16* x16   = h1buf + 2 * BH_;                            // [64][256][256] f16 (8MB)

  // zero: sync + h0 slot0 (L0 p=0 reads it) ; h1 slot0 (L1 p=1 reads it)
  hipMemsetAsync(d_ws, 0, 4096 + (size_t)BH_ * sizeof(f16), stream);
  hipMemsetAsync(h1buf, 0, (size_t)BH_ * sizeof(f16), stream);

  hipLaunchKernelGGL(cvt_x, dim3((B_ * T_ * I_) / (256 * 8)), dim3(256), 0, stream, x, x16);

  hipLaunchKernelGGL(lstm_persistent, dim3(256), dim3(512), 0, stream,
                     x16, W0x, W0h, b0, W1x, W1h, b1, h0buf, h1buf, sync);

  // final h1 = timestep T-1 -> slot (T)&1 = 0
  hipLaunchKernelGGL(out_gemm, dim3(8, 16), dim3(128), 0, stream,
                     h1buf, Wo, bo, (float*)d_out);
}

// Round 8
// 3178.727 us; speedup vs baseline: 2.5669x; 2.5669x over previous
//
#include <hip/hip_runtime.h>
#include <cstddef>

#define B_  64
#define T_  256
#define I_  256
#define H_  1024
#define C_  1000
#define BH_ (B_ * H_)
#define SLOTS_ 24          // h history ring length (reuse distance)
#define FENCE_MASK_ 7      // acquire-invalidate every 8th phase

typedef _Float16 f16;
typedef __attribute__((ext_vector_type(8))) _Float16 f16x8;
typedef __attribute__((ext_vector_type(4))) float f32x4;

__device__ __forceinline__ float sigmoid_(float v) { return 1.0f / (1.0f + __expf(-v)); }
__device__ __forceinline__ float tanh_(float v) {
  float e = __expf(-2.0f * fabsf(v));
  float t = (1.0f - e) / (1.0f + e);
  return copysignf(t, v);
}

// h store: agent-scope relaxed atomic store -> write-through dword (sc0 sc1).
// Leaves no dirty L2 lines; globally visible at MALL once vmcnt drains at
// __syncthreads. NOTE (R7 lesson): the LOAD side must stay cached -- atomic
// loads are per-lane fabric transactions, ~2.5x total runtime.
__device__ __forceinline__ void storeH2(f16* p, float a, float b) {
  union { f16 h[2]; unsigned u; } pk;
  pk.h[0] = (f16)a; pk.h[1] = (f16)b;
  __hip_atomic_store((unsigned*)p, pk.u, __ATOMIC_RELAXED, __HIP_MEMORY_SCOPE_AGENT);
}

// Two-level barrier (best measured: R3). All RELAXED atomics; release ordering
// of h stores before flag-add comes from __syncthreads' vmcnt(0) drain.
// The acquire fence (L1+L2 invalidate) runs only when do_fence!=0: with the
// 24-slot h history, stale cached copies of a slot are always purged by one of
// the every-8th-phase fences before that slot is reused (23 > 8).
__device__ __forceinline__ void grid_barrier(unsigned* sync, int bid, int phase,
                                             int do_fence) {
  __syncthreads();
  if (threadIdx.x == 0) {
    unsigned* master = sync;
    unsigned* bucket = sync + 32 * (1 + (bid & 7));   // 128B-spaced lines
    __hip_atomic_fetch_add(bucket, 1u, __ATOMIC_RELAXED, __HIP_MEMORY_SCOPE_AGENT);
    if (bid < 8) {
      const unsigned bt = 32u * (unsigned)(phase + 1);
      int g = 0;
      while (__hip_atomic_load(bucket, __ATOMIC_RELAXED, __HIP_MEMORY_SCOPE_AGENT) < bt) {
        __builtin_amdgcn_s_sleep(1);
        if (++g > (1 << 16)) break;
      }
      __hip_atomic_fetch_add(master, 1u, __ATOMIC_RELAXED, __HIP_MEMORY_SCOPE_AGENT);
    }
    const unsigned mt = 8u * (unsigned)(phase + 1);
    int g2 = 0;
    while (__hip_atomic_load(master, __ATOMIC_RELAXED, __HIP_MEMORY_SCOPE_AGENT) < mt) {
      __builtin_amdgcn_s_sleep(1);
      if (++g2 > (1 << 16)) break;
    }
    if (do_fence) __builtin_amdgcn_fence(__ATOMIC_ACQUIRE, "agent");
  }
  __syncthreads();
}

// One block = 512 threads = 8 waves = (K-split 4) x (N-split 2).
// Block tile: 32 batch rows x 64 gate-cols (4 gates x 16 units).
// Per-wave weights: (K/4) x 32 cols f16 = 128 VGPRs (L1) -> 2 waves/SIMD.
// CRITICAL: prologue loop must be FULLY unrolled so Wreg indexing is static
// (R2's `#pragma unroll 1` demoted Wreg to scratch -> 7 GB/launch re-fetch).
template<bool IS_L1>
__device__ __forceinline__ void role_main(
    const f16* __restrict__ x16,
    const float* __restrict__ Wx, const float* __restrict__ Wh,
    const float* __restrict__ bias,
    f16* __restrict__ h0hist, f16* __restrict__ h1hist,
    unsigned* sync, int bid, int nslots, int fence_mask,
    float* zbAll, float* cLDS, float* biasLDS)
{
  constexpr int KTOT = IS_L1 ? 64 : 40;   // k-tiles of 32 (L0: 8 x-tiles + 32 h-tiles)
  constexpr int NKT  = KTOT / 4;          // per-wave k-tiles (K-split over kq)
  constexpr int KX   = IS_L1 ? 1024 : 256;

  const int tid  = threadIdx.x;
  const int wv   = tid >> 6;          // 0..7
  const int nh   = wv >> 2;           // col-half (32 cols each)
  const int kq   = wv & 3;            // K quarter
  const int lane = tid & 63;
  const int c16  = lane & 15;
  const int quad = lane >> 4;
  const int rr7  = bid & 127;
  const int mgroup  = rr7 & 1;
  const int ubase   = (rr7 >> 1) * 16;
  const int rowbase = mgroup * 32;

  if (tid < 64) biasLDS[tid] = bias[(size_t)(tid >> 4) * H_ + ubase + (tid & 15)];
  cLDS[tid] = 0.0f;

  // ---- weight prologue: global fp32 -> per-wave LDS panel -> f16 B-frags in regs
  f16x8 Wreg[2][NKT];
  {
    f16* zpan = (f16*)zbAll + wv * 1024;   // private 2KB panel per wave
#pragma unroll
    for (int ii = 0; ii < NKT; ++ii) {
      const int kt = kq * NKT + ii;
#pragma unroll
      for (int rw = 0; rw < 16; ++rw) {
        const int krow  = rw * 2 + (lane >> 5);
        const int col32 = lane & 31;
        const int g = nh * 2 + (col32 >> 4);
        const int u = col32 & 15;
        const int k = kt * 32 + krow;
        float wval = (k < KX) ? Wx[((size_t)g * KX + k) * H_ + ubase + u]
                              : Wh[((size_t)g * H_ + (k - KX)) * H_ + ubase + u];
        zpan[krow * 32 + col32] = (f16)wval;
      }
#pragma unroll
      for (int nt = 0; nt < 2; ++nt) {
        f16x8 f;
#pragma unroll
        for (int j = 0; j < 8; ++j)
          f[j] = zpan[(quad * 8 + j) * 32 + nt * 16 + c16];  // B[n=lane&15][k=quad*8+j]
        Wreg[nt][ii] = f;
      }
    }
  }
  __syncthreads();

  const int ktbase = kq * NKT;
  const int row0 = rowbase + c16;

#pragma unroll 1
  for (int p = 0; p <= T_; ++p) {
    const bool active = IS_L1 ? (p >= 1) : (p < T_);
    if (active) {
      // slot map: h0[t] -> slot (t+1)%nslots ; h1[t] -> slot (t+1)%nslots.
      // L0 phase p: reads h0[p-1]=slot p%n, writes h0[p]=slot (p+1)%n.
      // L1 phase p: reads h0[p-1]=slot p%n, h1[p-2]=slot (p-1)%n,
      //             writes h1[p-1]=slot p%n.
      const int sp  = p % nslots;
      const int spm = (p - 1 + nslots) % nslots;
      const int spp = (p + 1) % nslots;
      const f16* __restrict__ hA = h0hist + (size_t)sp * BH_;
      const f16* __restrict__ hB = h1hist + (size_t)spm * BH_;
      f16* __restrict__ hdst = IS_L1 ? (h1hist + (size_t)sp  * BH_)
                                     : (h0hist + (size_t)spp * BH_);

      f16x8 Abuf[6][2];
      auto loadA = [&](int ii, int slot) {
        const int kt = ktbase + ii;
        const int k  = kt * 32 + quad * 8;
#pragma unroll
        for (int mt2 = 0; mt2 < 2; ++mt2) {
          const int row = row0 + mt2 * 16;
          if (!IS_L1 && k < 256) {          // x-part: immutable f16, cached
            Abuf[slot][mt2] = *(const f16x8*)(x16 + ((size_t)row * T_ + p) * I_ + k);
          } else if (IS_L1 && k >= 1024) {
            Abuf[slot][mt2] = *(const f16x8*)(hB + (size_t)row * H_ + (k - 1024));
          } else {
            const int kk = IS_L1 ? k : (k - 256);
            Abuf[slot][mt2] = *(const f16x8*)(hA + (size_t)row * H_ + kk);
          }
        }
      };

      f32x4 acc[2][2];
#pragma unroll
      for (int mt2 = 0; mt2 < 2; ++mt2)
#pragma unroll
        for (int nt = 0; nt < 2; ++nt)
          acc[mt2][nt] = (f32x4)0.0f;

      loadA(0, 0); loadA(1, 1); loadA(2, 2);
      loadA(3, 3); loadA(4, 4); loadA(5, 5);     // prefetch ring depth 6
#pragma unroll
      for (int i = 0; i < NKT; ++i) {
        const int sl = i % 6;
        const f16x8 a0 = Abuf[sl][0];
        const f16x8 a1 = Abuf[sl][1];
        if (i + 6 < NKT) loadA(i + 6, (i + 6) % 6);
        acc[0][0] = __builtin_amdgcn_mfma_f32_16x16x32_f16(a0, Wreg[0][i], acc[0][0], 0, 0, 0);
        acc[0][1] = __builtin_amdgcn_mfma_f32_16x16x32_f16(a0, Wreg[1][i], acc[0][1], 0, 0, 0);
        acc[1][0] = __builtin_amdgcn_mfma_f32_16x16x32_f16(a1, Wreg[0][i], acc[1][0], 0, 0, 0);
        acc[1][1] = __builtin_amdgcn_mfma_f32_16x16x32_f16(a1, Wreg[1][i], acc[1][1], 0, 0, 0);
      }

      // partial z -> LDS; region (nh*4 + kq) so stage-1 sums stride-1024 over kq
      float* zw = zbAll + (nh * 4 + kq) * 1024;
#pragma unroll
      for (int mt2 = 0; mt2 < 2; ++mt2)
#pragma unroll
        for (int nt = 0; nt < 2; ++nt)
#pragma unroll
          for (int e = 0; e < 4; ++e)
            zw[(mt2 * 2 + nt) * 256 + (quad * 4 + e) * 16 + c16] = acc[mt2][nt][e];

      __syncthreads();

      // stage 1: reduce 4 K-partials + bias, in place into kq=0 region
      {
        const int base = tid * 4;          // 512 thr x 4 = 2048 final z
        const int nh1  = base >> 10;
        const int off  = base & 1023;
        f32x4 s = (f32x4)0.0f;
#pragma unroll
        for (int q = 0; q < 4; ++q)
          s += *(const f32x4*)(zbAll + nh1 * 4096 + q * 1024 + off);
        const int nt1 = (off >> 8) & 1;
        const int c0  = off & 15;
        s += *(const f32x4*)(biasLDS + (nh1 * 2 + nt1) * 16 + c0);
        *(f32x4*)(zbAll + nh1 * 4096 + off) = s;
      }
      __syncthreads();

      // stage 2: fused gates; c stays in LDS; h published via write-through 4B stores
      {
        const int row = tid >> 4, u = tid & 15;
        const int mt2 = row >> 4, r16 = row & 15;
        const float z0 = zbAll[0 * 4096 + (mt2 * 2 + 0) * 256 + r16 * 16 + u];
        const float z1 = zbAll[0 * 4096 + (mt2 * 2 + 1) * 256 + r16 * 16 + u];
        const float z2 = zbAll[1 * 4096 + (mt2 * 2 + 0) * 256 + r16 * 16 + u];
        const float z3 = zbAll[1 * 4096 + (mt2 * 2 + 1) * 256 + r16 * 16 + u];
        const float cv = cLDS[tid];
        const float gt = tanh_(z0);
        const float iv = sigmoid_(z1);
        const float fv = sigmoid_(z2);
        const float ov = sigmoid_(z3);
        const float cn = gt * iv + cv * fv;
        cLDS[tid] = cn;
        const float hn = tanh_(cn) * ov;
        const float hn_hi = __shfl_down(hn, 1);
        if ((tid & 1) == 0)
          storeH2(hdst + (size_t)(rowbase + row) * H_ + ubase + u, hn, hn_hi);
      }
    } else {
      __syncthreads();   // keep barrier symmetry on inactive phases
    }
    // fence on every phase when nslots==2 (fallback), else every (mask+1)th
    const int do_fence = (nslots == 2) ? 1 : (((p & fence_mask) == fence_mask) ? 1 : 0);
    grid_barrier(sync, bid, p, do_fence);
  }
}

__global__ __launch_bounds__(512, 2)
void lstm_persistent(const f16* __restrict__ x16,
                     const float* __restrict__ W0x, const float* __restrict__ W0h, const float* __restrict__ b0,
                     const float* __restrict__ W1x, const float* __restrict__ W1h, const float* __restrict__ b1,
                     f16* h0hist, f16* h1hist, unsigned* sync, int nslots)
{
  __shared__ float zbAll[8192];    // 32KB: prologue panels / wave partial z / final z
  __shared__ float cLDS[512];
  __shared__ float biasLDS[64];
  const int bid = blockIdx.x;
  if (bid >= 128)
    role_main<true >(x16, W1x, W1h, b1, h0hist, h1hist, sync, bid, nslots, FENCE_MASK_, zbAll, cLDS, biasLDS);
  else
    role_main<false>(x16, W0x, W0h, b0, h0hist, h1hist, sync, bid, nslots, FENCE_MASK_, zbAll, cLDS, biasLDS);
}

// x fp32 -> f16, once
__global__ void cvt_x(const float* __restrict__ xin, f16* __restrict__ xo)
{
  const int i = (blockIdx.x * 256 + threadIdx.x) * 8;
  const float4 a = *(const float4*)(xin + i);
  const float4 b = *(const float4*)(xin + i + 4);
  f16x8 v;
  v[0] = (f16)a.x; v[1] = (f16)a.y; v[2] = (f16)a.z; v[3] = (f16)a.w;
  v[4] = (f16)b.x; v[5] = (f16)b.y; v[6] = (f16)b.z; v[7] = (f16)b.w;
  *(f16x8*)(xo + i) = v;
}

// out[b][c] = h1_final[b][:] . Wo[:][c] + bo[c]   (fp32 vector math)
__global__ void out_gemm(const f16* __restrict__ h1,
                         const float* __restrict__ Wo, const float* __restrict__ bo,
                         float* __restrict__ out)
{
  __shared__ float ht[1024][8];
  const int tid = threadIdx.x;    // 128 threads
  const int b0r = blockIdx.y * 4;
  for (int i = tid; i < 4096; i += 128) {
    const int rr = i >> 10, k = i & 1023;
    ht[k][rr] = (float)h1[(size_t)(b0r + rr) * H_ + k];
  }
  __syncthreads();
  const int c = blockIdx.x * 125 + tid;
  if (tid < 125) {
    float a0 = 0.f, a1 = 0.f, a2 = 0.f, a3 = 0.f;
#pragma unroll 4
    for (int k = 0; k < 1024; ++k) {
      const float w = Wo[(size_t)k * C_ + c];
      a0 += ht[k][0] * w;
      a1 += ht[k][1] * w;
      a2 += ht[k][2] * w;
      a3 += ht[k][3] * w;
    }
    const float bb = bo[c];
    out[(size_t)(b0r + 0) * C_ + c] = a0 + bb;
    out[(size_t)(b0r + 1) * C_ + c] = a1 + bb;
    out[(size_t)(b0r + 2) * C_ + c] = a2 + bb;
    out[(size_t)(b0r + 3) * C_ + c] = a3 + bb;
  }
}

extern "C" void kernel_launch(void* const* d_in, const int* in_sizes, int n_in,
                              void* d_out, int out_size, void* d_ws, size_t ws_size,
                              hipStream_t stream)
{
  const float* x   = (const float*)d_in[0];
  const float* W0x = (const float*)d_in[1];
  const float* W0h = (const float*)d_in[2];
  const float* b0  = (const float*)d_in[3];
  const float* W1x = (const float*)d_in[4];
  const float* W1h = (const float*)d_in[5];
  const float* b1  = (const float*)d_in[6];
  const float* Wo  = (const float*)d_in[7];
  const float* bo  = (const float*)d_in[8];

  const size_t xB = (size_t)B_ * T_ * I_ * sizeof(f16);            // 8 MB
  const size_t need24 = 4096 + (size_t)2 * SLOTS_ * BH_ * sizeof(f16) + xB;
  const int nslots = (ws_size >= need24) ? SLOTS_ : 2;
  const size_t histB = (size_t)nslots * BH_ * sizeof(f16);

  unsigned* sync  = (unsigned*)d_ws;                 // barrier counters (4KB)
  f16* h0hist = (f16*)((char*)d_ws + 4096);
  f16* h1hist = (f16*)((char*)h0hist + histB);
  f16* x16    = (f16*)((char*)h1hist + histB);

  // zero: sync + h0 slot0 (contiguous); h1 slot0
  hipMemsetAsync(d_ws, 0, 4096 + (size_t)BH_ * sizeof(f16), stream);
  hipMemsetAsync(h1hist, 0, (size_t)BH_ * sizeof(f16), stream);

  hipLaunchKernelGGL(cvt_x, dim3((B_ * T_ * I_) / (256 * 8)), dim3(256), 0, stream, x, x16);

  hipLaunchKernelGGL(lstm_persistent, dim3(256), dim3(512), 0, stream,
                     x16, W0x, W0h, b0, W1x, W1h, b1, h0hist, h1hist, sync, nslots);

  // final h1 = timestep T-1 -> written at phase T -> slot T % nslots
  f16* h1fin = h1hist + (size_t)(T_ % nslots) * BH_;
  hipLaunchKernelGGL(out_gemm, dim3(8, 16), dim3(128), 0, stream,
                     h1fin, Wo, bo, (float*)d_out);
}